// Round 1
// baseline (535.758 us; speedup 1.0000x reference)
//
#include <hip/hip_runtime.h>

// Problem constants
#define NB   4      // batch
#define NN   4      // contexts per pixel
#define CCh  256    // Cc
#define CFh  512    // Cf
#define HH   128
#define WW   128
#define PLO  4096   // 64*64 low-res pixels
#define PHI  16384  // 128*128 hi-res pixels

typedef __bf16 bf16;
typedef __bf16 bf16x8 __attribute__((ext_vector_type(8)));
typedef float  f32x4  __attribute__((ext_vector_type(4)));
typedef float  f32x2  __attribute__((ext_vector_type(2)));

__device__ __forceinline__ void gll16(const void* g, void* lds) {
    __builtin_amdgcn_global_load_lds(
        (const __attribute__((address_space(1))) void*)g,
        (__attribute__((address_space(3))) void*)lds, 16, 0, 0);
}

// ---------------------------------------------------------------------------
// prep 1: M_qk[c][f] = sum_o Wc_w[o][c] * Wf_w[o][f]  (bf16 out)
//         d_qk[c]    = sum_o Wc_w[o][c] * Wf_b[o]     (fp32, parallel reduce)
__global__ void prep_mqk(const float* __restrict__ Wc_w, const float* __restrict__ Wf_w,
                         const float* __restrict__ Wf_b, bf16* __restrict__ M_qk,
                         float* __restrict__ d_qk) {
    __shared__ float red[256];
    int c = blockIdx.y;
    int f = blockIdx.x * 256 + threadIdx.x;
    float s = 0.f;
    for (int o = 0; o < CCh; ++o)
        s += Wc_w[o * CCh + c] * Wf_w[o * CFh + f];
    M_qk[c * CFh + f] = (bf16)s;
    if (blockIdx.x == 0) {          // block-uniform branch: barriers are safe
        int o = threadIdx.x;
        red[o] = Wc_w[o * CCh + c] * Wf_b[o];
        __syncthreads();
        for (int st = 128; st > 0; st >>= 1) {
            if (threadIdx.x < st) red[threadIdx.x] += red[threadIdx.x + st];
            __syncthreads();
        }
        if (threadIdx.x == 0) d_qk[c] = red[0];
    }
}

// ---------------------------------------------------------------------------
// prep 2: transpose mainstream [B][512][4096] fp32 -> ms_t [B][4096][512] bf16
__global__ void prep_ms(const float* __restrict__ ms, bf16* __restrict__ ms_t) {
    __shared__ float tile[32][33];
    int b = blockIdx.z;
    int p0 = blockIdx.x * 32, f0 = blockIdx.y * 32;
    int tx = threadIdx.x;
    int r = tx >> 5, cc = tx & 31;
    const float* src = ms + (size_t)b * CFh * PLO;
#pragma unroll
    for (int q = 0; q < 4; ++q) {
        int fl = q * 8 + r;
        tile[fl][cc] = src[(size_t)(f0 + fl) * PLO + p0 + cc];
    }
    __syncthreads();
    bf16* dst = ms_t + (size_t)b * PLO * CFh;
#pragma unroll
    for (int q = 0; q < 4; ++q) {
        int pl = q * 8 + r;
        dst[(size_t)(p0 + pl) * CFh + f0 + cc] = (bf16)tile[cc][pl];
    }
}

// ---------------------------------------------------------------------------
// prep 3: pack Wv_w [256][512][3][3] fp32 -> Wv_p [9][256][512] bf16; zero zerobuf
__global__ void prep_wv(const float* __restrict__ Wv_w, bf16* __restrict__ Wv_p,
                        bf16* __restrict__ zerob) {
    int tid = blockIdx.x * 256 + threadIdx.x;   // t-major: (t*256 + c)*512 + f
    int t = tid / (CCh * CFh);
    int rem = tid % (CCh * CFh);
    int c = rem / CFh, f = rem % CFh;
    Wv_p[tid] = (bf16)Wv_w[(size_t)(c * CFh + f) * 9 + t];
    if (tid < 1024) zerob[tid] = (bf16)0.f;
}

// ---------------------------------------------------------------------------
// GEMM: M=channels(128-tile), N=pixels(128-tile), BK=32, 256 thr = 4 waves.
// grid (32, 2, 8): z<4 -> conv, b=z, ALL 9 taps accumulated in one block,
//   writes fp32 v (+Wv_b bias) to v[b][256][4096].
// z>=4 -> qk (1 tap), b=z-4, writes bf16 (+d_qk bias) to qk_out.
// Double-buffered LDS, 2-phase pipeline: stage(next) issued before compute(cur),
// ONE __syncthreads (vmcnt drain) per K-step.
__global__ __launch_bounds__(256) void gemm_kernel(
    const bf16* __restrict__ Wv_p,   // [9][256][512]
    const bf16* __restrict__ M_qk,   // [256][512]
    const bf16* __restrict__ ms_t,   // [B][4096][512]
    const float* __restrict__ d_qk,
    const float* __restrict__ Wv_b,  // [256]
    const bf16* __restrict__ zerob,
    float* __restrict__ v_out, bf16* __restrict__ qk_out) {
    __shared__ __align__(16) bf16 Alds[2][128 * 32];  // [buf][c][f]
    __shared__ __align__(16) bf16 Blds[2][128 * 32];  // [buf][p][f]

    const int tx = threadIdx.x;
    const int wave = tx >> 6, lane = tx & 63;
    const int ptile = blockIdx.x, ctile = blockIdx.y;
    const int z = blockIdx.z;
    const int mode = (z >= 4);                 // 0=conv(9 taps), 1=qk
    const int b = mode ? (z - 4) : z;
    const int NIT = mode ? 16 : 144;           // ntaps * 16 K-steps

    const bf16* Wbase = mode ? M_qk : Wv_p;
    const bf16* msb = ms_t + (size_t)b * PLO * CFh;

    // staging lane mapping: issue q covers bytes [wave*2048 + q*1024, +1024)
    int idx0 = wave * 2048 + lane * 16;
    int idx1 = idx0 + 1024;
    int rA0 = idx0 >> 6, fq0 = (idx0 >> 4) & 3;   // row 0..127, 16B-chunk 0..3
    int rA1 = idx1 >> 6, fq1 = (idx1 >> 4) & 3;
    const size_t aoff0 = (size_t)(ctile * 128 + rA0) * CFh + fq0 * 8;
    const size_t aoff1 = (size_t)(ctile * 128 + rA1) * CFh + fq1 * 8;

    const int p0 = ptile * 128 + rA0, p1 = ptile * 128 + rA1;
    const int i0_ = p0 >> 6, j0_ = p0 & 63;
    const int i1_ = p1 >> 6, j1_ = p1 & 63;

    f32x4 acc[4][4];
#pragma unroll
    for (int mi = 0; mi < 4; ++mi)
#pragma unroll
        for (int ni = 0; ni < 4; ++ni) acc[mi][ni] = f32x4{0.f, 0.f, 0.f, 0.f};

    const int wm = wave >> 1, wn = wave & 1;
    const int quad = lane >> 4, l15 = lane & 15;

    // per-tap source pointers (updated once every 16 K-steps; uniform branch)
    const bf16* bs0c; const bf16* bs1c; const bf16* Wtc;
#define SET_TAP(tt) do {                                                        \
        int t_ = (tt);                                                          \
        int dy = mode ? 0 : (t_ / 3 - 1);                                       \
        int dx = mode ? 0 : (t_ % 3 - 1);                                       \
        int si0 = i0_ + dy, sj0 = j0_ + dx;                                     \
        int si1 = i1_ + dy, sj1 = j1_ + dx;                                     \
        bs0c = ((unsigned)si0 < 64u && (unsigned)sj0 < 64u)                     \
                   ? msb + (size_t)(si0 * 64 + sj0) * CFh + fq0 * 8 : zerob;    \
        bs1c = ((unsigned)si1 < 64u && (unsigned)sj1 < 64u)                     \
                   ? msb + (size_t)(si1 * 64 + sj1) * CFh + fq1 * 8 : zerob;    \
        Wtc = Wbase + (size_t)t_ * CCh * CFh;                                   \
    } while (0)

    SET_TAP(0);
    {   // prologue: stage K-step 0 into buf 0
        char* lA = (char*)(&Alds[0][0]) + wave * 2048;
        char* lB = (char*)(&Blds[0][0]) + wave * 2048;
        gll16(Wtc + aoff0, lA);
        gll16(Wtc + aoff1, lA + 1024);
        gll16(bs0c, lB);
        gll16(bs1c, lB + 1024);
    }
    __syncthreads();   // vmcnt(0) drain: buf0 ready

    for (int it = 0; it < NIT; ++it) {
        const int buf = it & 1;
        const int nx = it + 1;
        if (nx < NIT) {            // issue next stage BEFORE compute (T3 2-phase)
            if ((nx & 15) == 0) SET_TAP(nx >> 4);
            const int f0 = (nx & 15) * 32;
            char* lA = (char*)(&Alds[buf ^ 1][0]) + wave * 2048;
            char* lB = (char*)(&Blds[buf ^ 1][0]) + wave * 2048;
            gll16(Wtc + aoff0 + f0, lA);
            gll16(Wtc + aoff1 + f0, lA + 1024);
            gll16(bs0c + f0, lB);
            gll16(bs1c + f0, lB + 1024);
        }
        const bf16* Ab = &Alds[buf][0];
        const bf16* Bb = &Blds[buf][0];
        bf16x8 af[4], bfr[4];
#pragma unroll
        for (int mi = 0; mi < 4; ++mi)
            af[mi] = *(const bf16x8*)&Ab[(wm * 64 + mi * 16 + l15) * 32 + quad * 8];
#pragma unroll
        for (int ni = 0; ni < 4; ++ni)
            bfr[ni] = *(const bf16x8*)&Bb[(wn * 64 + ni * 16 + l15) * 32 + quad * 8];
#pragma unroll
        for (int mi = 0; mi < 4; ++mi)
#pragma unroll
            for (int ni = 0; ni < 4; ++ni)
                acc[mi][ni] = __builtin_amdgcn_mfma_f32_16x16x32_bf16(
                    af[mi], bfr[ni], acc[mi][ni], 0, 0, 0);
        __syncthreads();   // one barrier per K-step: next buf staged + cur reads done
    }
#undef SET_TAP

    // C/D layout: col = lane&15 (pixel), row = quad*4 + r (channel)
    if (mode) {
        bf16* obase = qk_out + (size_t)b * CCh * PLO;
#pragma unroll
        for (int mi = 0; mi < 4; ++mi) {
            int cb = ctile * 128 + wm * 64 + mi * 16 + quad * 4;
#pragma unroll
            for (int ni = 0; ni < 4; ++ni) {
                int p = ptile * 128 + wn * 64 + ni * 16 + l15;
                bf16* op = obase + (size_t)cb * PLO + p;
#pragma unroll
                for (int r = 0; r < 4; ++r)
                    op[(size_t)r * PLO] = (bf16)(acc[mi][ni][r] + d_qk[cb + r]);
            }
        }
    } else {
        float* obase = v_out + (size_t)b * CCh * PLO;
#pragma unroll
        for (int mi = 0; mi < 4; ++mi) {
            int cb = ctile * 128 + wm * 64 + mi * 16 + quad * 4;
#pragma unroll
            for (int ni = 0; ni < 4; ++ni) {
                int p = ptile * 128 + wn * 64 + ni * 16 + l15;
                float* op = obase + (size_t)cb * PLO + p;
#pragma unroll
                for (int r = 0; r < 4; ++r)
                    op[(size_t)r * PLO] = acc[mi][ni][r] + Wv_b[cb + r];
            }
        }
    }
}

// ---------------------------------------------------------------------------
// attention: block = 512 thr, 32 pixels (one 32-wide w strip).
// Thread: 2 consecutive w-pixels (f32x2) x 8 channels x 4 n held in VGPRs.
// vals = 64 VGPR -> target <=128 total -> 4 waves/SIMD (launch_bounds(512,4)).
__global__ __launch_bounds__(512, 4) void attn_kernel(
    const float* __restrict__ ctx,   // [4][4][256][128][128]
    const bf16* __restrict__ qk,     // [4][256][4096]
    const float* __restrict__ v,     // [4][256][4096] conv+bias, final
    float* __restrict__ out) {       // [4][256][128][128]
    __shared__ f32x2 swred[4][8][16];  // [n][wave][pq]
    const int tx = threadIdx.x;
    const int pq = tx & 15;            // which 2-pixel group
    const int cc = tx >> 4;            // channel chunk 0..31
    const int lane = tx & 63;
    const int wv = tx >> 6;
    const int quad = lane >> 4;

    const int pbase = blockIdx.x << 5;     // 32 px per block
    const int b = pbase >> 14;
    const int rem = pbase & 16383;
    const int hh = rem >> 7;
    const int w0 = rem & 127;              // 0,32,64,96
    const int wq = w0 + pq * 2;
    const int i = hh >> 1, j = wq >> 1;    // one lo-res pixel per thread

    const int c0 = cc * 8;
    const size_t NSTR = (size_t)CCh * PHI;
    const float* cbase = ctx + (size_t)b * NN * NSTR + (size_t)c0 * PHI
                             + (size_t)hh * WW + wq;
    const bf16* qkb = qk + ((size_t)b * CCh + c0) * PLO + i * 64 + j;
    const float* vbp = v + ((size_t)b * CCh + c0) * PLO + i * 64 + j;

    f32x2 vals[4][8];
    f32x2 s[4];
#pragma unroll
    for (int n = 0; n < 4; ++n) s[n] = f32x2{0.f, 0.f};

#pragma unroll
    for (int cj = 0; cj < 8; ++cj) {
        float q = (float)qkb[(size_t)cj * PLO];
        f32x2 qv = {q, q};
#pragma unroll
        for (int n = 0; n < 4; ++n) {
            vals[n][cj] = *(const f32x2*)(cbase + n * NSTR + (size_t)cj * PHI);
            s[n] += vals[n][cj] * qv;
        }
    }
    // reduce over the 4 quads within each wave (cc bits 0..1 live in lane bits 4..5)
#pragma unroll
    for (int n = 0; n < 4; ++n) {
#pragma unroll
        for (int m = 16; m <= 32; m <<= 1) {
            f32x2 t;
            t[0] = __shfl_xor(s[n][0], m);
            t[1] = __shfl_xor(s[n][1], m);
            s[n] += t;
        }
    }
    // lane with quad q publishes n=q for its wave
    f32x2 sq = (quad == 0) ? s[0] : (quad == 1) ? s[1] : (quad == 2) ? s[2] : s[3];
    swred[quad][wv][pq] = sq;
    __syncthreads();

    f32x2 t4[4];
#pragma unroll
    for (int n = 0; n < 4; ++n) {
        f32x2 a = swred[n][0][pq];
#pragma unroll
        for (int w = 1; w < 8; ++w) a += swred[n][w][pq];
        t4[n] = a;
    }
    f32x2 mx;
#pragma unroll
    for (int k = 0; k < 2; ++k)
        mx[k] = fmaxf(fmaxf(t4[0][k], t4[1][k]), fmaxf(t4[2][k], t4[3][k]));
    f32x2 e[4];
#pragma unroll
    for (int n = 0; n < 4; ++n)
#pragma unroll
        for (int k = 0; k < 2; ++k) e[n][k] = __expf(t4[n][k] - mx[k]);
    f32x2 ssum = e[0] + e[1] + e[2] + e[3];
    f32x2 rs;
    rs[0] = 1.f / ssum[0];
    rs[1] = 1.f / ssum[1];
    f32x2 a4[4];
#pragma unroll
    for (int n = 0; n < 4; ++n) a4[n] = e[n] * rs;

    float* outp = out + ((size_t)b * CCh + c0) * PHI + (size_t)hh * WW + wq;
#pragma unroll
    for (int cj = 0; cj < 8; ++cj) {
        float vvv = vbp[(size_t)cj * PLO];
        f32x2 o = vals[0][cj] * a4[0] + vals[1][cj] * a4[1] +
                  vals[2][cj] * a4[2] + vals[3][cj] * a4[3] +
                  f32x2{vvv, vvv};
        *(f32x2*)(outp + (size_t)cj * PHI) = o;
    }
}

// ---------------------------------------------------------------------------
extern "C" void kernel_launch(void* const* d_in, const int* in_sizes, int n_in,
                              void* d_out, int out_size, void* d_ws, size_t ws_size,
                              hipStream_t stream) {
    const float* ctx  = (const float*)d_in[0];
    const float* ms   = (const float*)d_in[1];
    const float* Wc_w = (const float*)d_in[2];
    // d_in[3] = Wc_b: constant across n at each pixel -> cancels in softmax.
    const float* Wf_w = (const float*)d_in[4];
    const float* Wf_b = (const float*)d_in[5];
    const float* Wv_w = (const float*)d_in[6];
    const float* Wv_b = (const float*)d_in[7];
    float* out = (float*)d_out;

    char* ws = (char*)d_ws;
    bf16*  ms_t  = (bf16*)ws;                     // 16,777,216 B
    bf16*  Wv_p  = (bf16*)(ws + 16777216);        //  2,359,296 B
    bf16*  M_qk  = (bf16*)(ws + 19136512);        //    262,144 B
    float* d_qk  = (float*)(ws + 19398656);       //      1,024 B
    bf16*  zerob = (bf16*)(ws + 19399680);        //      2,048 B
    bf16*  qk    = (bf16*)(ws + 19401728);        //  8,388,608 B
    float* v     = (float*)(ws + 27790336);       // 16,777,216 B (total ~44.6 MB)

    prep_mqk<<<dim3(2, 256), 256, 0, stream>>>(Wc_w, Wf_w, Wf_b, M_qk, d_qk);
    prep_ms<<<dim3(128, 16, 4), 256, 0, stream>>>(ms, ms_t);
    prep_wv<<<dim3(4608), 256, 0, stream>>>(Wv_w, Wv_p, zerob);
    gemm_kernel<<<dim3(32, 2, 8), 256, 0, stream>>>(Wv_p, M_qk, ms_t, d_qk,
                                                    Wv_b, zerob, v, qk);
    attn_kernel<<<dim3(2048), 512, 0, stream>>>(ctx, qk, v, out);
}

// Round 2
// 527.756 us; speedup vs baseline: 1.0152x; 1.0152x over previous
//
#include <hip/hip_runtime.h>

// Problem constants
#define NB   4      // batch
#define NN   4      // contexts per pixel
#define CCh  256    // Cc
#define CFh  512    // Cf
#define HH   128
#define WW   128
#define PLO  4096   // 64*64 low-res pixels
#define PHI  16384  // 128*128 hi-res pixels

typedef __bf16 bf16;
typedef __bf16 bf16x8 __attribute__((ext_vector_type(8)));
typedef float  f32x4  __attribute__((ext_vector_type(4)));
typedef float  f32x2  __attribute__((ext_vector_type(2)));

__device__ __forceinline__ void gll16(const void* g, void* lds) {
    __builtin_amdgcn_global_load_lds(
        (const __attribute__((address_space(1))) void*)g,
        (__attribute__((address_space(3))) void*)lds, 16, 0, 0);
}

// ---------------------------------------------------------------------------
// prep 1: M_qk[c][f] = sum_o Wc_w[o][c] * Wf_w[o][f]  (bf16 out)
//         d_qk[c]    = sum_o Wc_w[o][c] * Wf_b[o]     (fp32, parallel reduce)
__global__ void prep_mqk(const float* __restrict__ Wc_w, const float* __restrict__ Wf_w,
                         const float* __restrict__ Wf_b, bf16* __restrict__ M_qk,
                         float* __restrict__ d_qk) {
    __shared__ float red[256];
    int c = blockIdx.y;
    int f = blockIdx.x * 256 + threadIdx.x;
    float s = 0.f;
    for (int o = 0; o < CCh; ++o)
        s += Wc_w[o * CCh + c] * Wf_w[o * CFh + f];
    M_qk[c * CFh + f] = (bf16)s;
    if (blockIdx.x == 0) {          // block-uniform branch: barriers are safe
        int o = threadIdx.x;
        red[o] = Wc_w[o * CCh + c] * Wf_b[o];
        __syncthreads();
        for (int st = 128; st > 0; st >>= 1) {
            if (threadIdx.x < st) red[threadIdx.x] += red[threadIdx.x + st];
            __syncthreads();
        }
        if (threadIdx.x == 0) d_qk[c] = red[0];
    }
}

// ---------------------------------------------------------------------------
// prep 2: transpose mainstream [B][512][4096] fp32 -> ms_t [B][4096][512] bf16
__global__ void prep_ms(const float* __restrict__ ms, bf16* __restrict__ ms_t) {
    __shared__ float tile[32][33];
    int b = blockIdx.z;
    int p0 = blockIdx.x * 32, f0 = blockIdx.y * 32;
    int tx = threadIdx.x;
    int r = tx >> 5, cc = tx & 31;
    const float* src = ms + (size_t)b * CFh * PLO;
#pragma unroll
    for (int q = 0; q < 4; ++q) {
        int fl = q * 8 + r;
        tile[fl][cc] = src[(size_t)(f0 + fl) * PLO + p0 + cc];
    }
    __syncthreads();
    bf16* dst = ms_t + (size_t)b * PLO * CFh;
#pragma unroll
    for (int q = 0; q < 4; ++q) {
        int pl = q * 8 + r;
        dst[(size_t)(p0 + pl) * CFh + f0 + cc] = (bf16)tile[cc][pl];
    }
}

// ---------------------------------------------------------------------------
// prep 3: pack Wv_w [256][512][3][3] fp32 -> Wv_p [9][256][512] bf16; zero zerobuf
__global__ void prep_wv(const float* __restrict__ Wv_w, bf16* __restrict__ Wv_p,
                        bf16* __restrict__ zerob) {
    int tid = blockIdx.x * 256 + threadIdx.x;   // t-major: (t*256 + c)*512 + f
    int t = tid / (CCh * CFh);
    int rem = tid % (CCh * CFh);
    int c = rem / CFh, f = rem % CFh;
    Wv_p[tid] = (bf16)Wv_w[(size_t)(c * CFh + f) * 9 + t];
    if (tid < 1024) zerob[tid] = (bf16)0.f;
}

// ---------------------------------------------------------------------------
// GEMM: M=channels(128-tile), N=pixels(64-tile), BK=32, 256 thr = 4 waves.
// grid (64, 2, 8): z<4 -> conv, b=z, all 9 taps accumulated (NIT=144),
//   writes fp32 v (+Wv_b) to v[b][256][4096].
// z>=4 -> qk (NIT=16), b=z-4, writes bf16 (+d_qk) to qk_out.
// BN=64 => one B-tile = one lo-res row (si=ptile+dy is wave-uniform).
// Conv grid = 512 blocks (2/CU) to restore cross-block latency hiding.
// Double-buffered LDS, 2-phase pipeline, ONE __syncthreads per K-step.
__global__ __launch_bounds__(256) void gemm_kernel(
    const bf16* __restrict__ Wv_p,   // [9][256][512]
    const bf16* __restrict__ M_qk,   // [256][512]
    const bf16* __restrict__ ms_t,   // [B][4096][512]
    const float* __restrict__ d_qk,
    const float* __restrict__ Wv_b,  // [256]
    const bf16* __restrict__ zerob,
    float* __restrict__ v_out, bf16* __restrict__ qk_out) {
    __shared__ __align__(16) bf16 Alds[2][128 * 32];  // [buf][c][f]  8KB each
    __shared__ __align__(16) bf16 Blds[2][64 * 32];   // [buf][p][f]  4KB each

    const int tx = threadIdx.x;
    const int wave = tx >> 6, lane = tx & 63;
    const int ptile = blockIdx.x, ctile = blockIdx.y;
    const int z = blockIdx.z;
    const int mode = (z >= 4);                 // 0=conv(9 taps), 1=qk
    const int b = mode ? (z - 4) : z;
    const int NIT = mode ? 16 : 144;           // ntaps * 16 K-steps

    const bf16* Wbase = mode ? M_qk : Wv_p;
    const bf16* msb = ms_t + (size_t)b * PLO * CFh;

    // A staging: issue q covers bytes [wave*2048 + q*1024, +1024) of 8KB tile
    int idx0 = wave * 2048 + lane * 16;
    int idx1 = idx0 + 1024;
    int rA0 = idx0 >> 6, fq0 = (idx0 >> 4) & 3;   // row 0..127, 16B-chunk 0..3
    int rA1 = idx1 >> 6, fq1 = (idx1 >> 4) & 3;
    const size_t aoff0 = (size_t)(ctile * 128 + rA0) * CFh + fq0 * 8;
    const size_t aoff1 = (size_t)(ctile * 128 + rA1) * CFh + fq1 * 8;
    // B staging: one issue, wave covers bytes [wave*1024, +1024) of 4KB tile
    const int rB = wave * 16 + (lane >> 2);       // row 0..63
    const int fqB = lane & 3;

    f32x4 acc[4][2];
#pragma unroll
    for (int mi = 0; mi < 4; ++mi)
#pragma unroll
        for (int ni = 0; ni < 2; ++ni) acc[mi][ni] = f32x4{0.f, 0.f, 0.f, 0.f};

    const int wm = wave >> 1, wn = wave & 1;
    const int quad = lane >> 4, l15 = lane & 15;

    const bf16* bsC; const bf16* Wtc;
#define SET_TAP(tt) do {                                                        \
        int t_ = (tt);                                                          \
        int dy = mode ? 0 : (t_ / 3 - 1);                                       \
        int dx = mode ? 0 : (t_ % 3 - 1);                                       \
        int si = ptile + dy, sj = rB + dx;                                      \
        bsC = ((unsigned)si < 64u && (unsigned)sj < 64u)                        \
                  ? msb + (size_t)(si * 64 + sj) * CFh + fqB * 8 : zerob;       \
        Wtc = Wbase + (size_t)t_ * CCh * CFh;                                   \
    } while (0)

    SET_TAP(0);
    {   // prologue: stage K-step 0 into buf 0
        char* lA = (char*)(&Alds[0][0]) + wave * 2048;
        char* lB = (char*)(&Blds[0][0]) + wave * 1024;
        gll16(Wtc + aoff0, lA);
        gll16(Wtc + aoff1, lA + 1024);
        gll16(bsC, lB);
    }
    __syncthreads();   // vmcnt(0) drain: buf0 ready

    for (int it = 0; it < NIT; ++it) {
        const int buf = it & 1;
        const int nx = it + 1;
        if (nx < NIT) {            // issue next stage BEFORE compute (T3 2-phase)
            if ((nx & 15) == 0) SET_TAP(nx >> 4);
            const int f0 = (nx & 15) * 32;
            char* lA = (char*)(&Alds[buf ^ 1][0]) + wave * 2048;
            char* lB = (char*)(&Blds[buf ^ 1][0]) + wave * 1024;
            gll16(Wtc + aoff0 + f0, lA);
            gll16(Wtc + aoff1 + f0, lA + 1024);
            gll16(bsC + f0, lB);
        }
        const bf16* Ab = &Alds[buf][0];
        const bf16* Bb = &Blds[buf][0];
        bf16x8 af[4], bfr[2];
#pragma unroll
        for (int mi = 0; mi < 4; ++mi)
            af[mi] = *(const bf16x8*)&Ab[(wm * 64 + mi * 16 + l15) * 32 + quad * 8];
#pragma unroll
        for (int ni = 0; ni < 2; ++ni)
            bfr[ni] = *(const bf16x8*)&Bb[(wn * 32 + ni * 16 + l15) * 32 + quad * 8];
#pragma unroll
        for (int mi = 0; mi < 4; ++mi)
#pragma unroll
            for (int ni = 0; ni < 2; ++ni)
                acc[mi][ni] = __builtin_amdgcn_mfma_f32_16x16x32_bf16(
                    af[mi], bfr[ni], acc[mi][ni], 0, 0, 0);
        __syncthreads();   // one barrier per K-step
    }
#undef SET_TAP

    // C/D layout: col = lane&15 (pixel), row = quad*4 + r (channel)
    if (mode) {
        bf16* obase = qk_out + (size_t)b * CCh * PLO;
#pragma unroll
        for (int mi = 0; mi < 4; ++mi) {
            int cb = ctile * 128 + wm * 64 + mi * 16 + quad * 4;
#pragma unroll
            for (int ni = 0; ni < 2; ++ni) {
                int p = ptile * 64 + wn * 32 + ni * 16 + l15;
                bf16* op = obase + (size_t)cb * PLO + p;
#pragma unroll
                for (int r = 0; r < 4; ++r)
                    op[(size_t)r * PLO] = (bf16)(acc[mi][ni][r] + d_qk[cb + r]);
            }
        }
    } else {
        float* obase = v_out + (size_t)b * CCh * PLO;
#pragma unroll
        for (int mi = 0; mi < 4; ++mi) {
            int cb = ctile * 128 + wm * 64 + mi * 16 + quad * 4;
#pragma unroll
            for (int ni = 0; ni < 2; ++ni) {
                int p = ptile * 64 + wn * 32 + ni * 16 + l15;
                float* op = obase + (size_t)cb * PLO + p;
#pragma unroll
                for (int r = 0; r < 4; ++r)
                    op[(size_t)r * PLO] = acc[mi][ni][r] + Wv_b[cb + r];
            }
        }
    }
}

// ---------------------------------------------------------------------------
// attention: block = 512 thr, 32 px (one 32-wide w strip). 2048 blocks.
// Thread: 4 consecutive w-pixels (f32x4) x 4 channels x 4 n held in VGPRs.
// vals = 64 VGPR; total ~110 -> launch_bounds(512,4) fits 128 -> 4 waves/SIMD.
// ctx loads: 16B/lane, 8 lanes contiguous = 128B (full line) per channel plane.
__global__ __launch_bounds__(512, 4) void attn_kernel(
    const float* __restrict__ ctx,   // [4][4][256][128][128]
    const bf16* __restrict__ qk,     // [4][256][4096]
    const float* __restrict__ v,     // [4][256][4096] conv+bias, final
    float* __restrict__ out) {       // [4][256][128][128]
    __shared__ f32x4 swred[4][8][8];   // [n][wave][pq]  4KB
    const int tx = threadIdx.x;
    const int pq = tx & 7;             // which 4-pixel group (0..7)
    const int cc = tx >> 3;            // channel chunk 0..63 (4 ch each)
    const int lane = tx & 63;
    const int wv = tx >> 6;
    const int g = lane >> 3;           // cc-low group 0..7 within wave

    const int pbase = blockIdx.x << 5;     // 32 px per block
    const int b = pbase >> 14;
    const int rem = pbase & 16383;
    const int hh = rem >> 7;
    const int w0 = rem & 127;              // 0,32,64,96
    const int wq = w0 + pq * 4;
    const int i = hh >> 1, j0 = wq >> 1;   // j0 even: lo-px j0, j0+1

    const int c0 = cc * 4;
    const size_t NSTR = (size_t)CCh * PHI;
    const float* cbase = ctx + (size_t)b * NN * NSTR + (size_t)c0 * PHI
                             + (size_t)hh * WW + wq;
    const bf16* qkb = qk + ((size_t)b * CCh + c0) * PLO + i * 64 + j0;
    const float* vbp = v + ((size_t)b * CCh + c0) * PLO + i * 64 + j0;

    f32x4 vals[4][4];
    f32x4 s[4];
#pragma unroll
    for (int n = 0; n < 4; ++n) s[n] = f32x4{0.f, 0.f, 0.f, 0.f};

#pragma unroll
    for (int cj = 0; cj < 4; ++cj) {
        unsigned qw = *(const unsigned*)(qkb + (size_t)cj * PLO);
        float qa = __uint_as_float(qw << 16);
        float qb = __uint_as_float(qw & 0xffff0000u);
        f32x4 qv = {qa, qa, qb, qb};
#pragma unroll
        for (int n = 0; n < 4; ++n) {
            vals[n][cj] = *(const f32x4*)(cbase + n * NSTR + (size_t)cj * PHI);
            s[n] += vals[n][cj] * qv;
        }
    }
    // in-wave reduce over cc bits 0..2 (lane bits 3..5)
#pragma unroll
    for (int n = 0; n < 4; ++n) {
#pragma unroll
        for (int m = 8; m <= 32; m <<= 1) {
            f32x4 t;
            t[0] = __shfl_xor(s[n][0], m);
            t[1] = __shfl_xor(s[n][1], m);
            t[2] = __shfl_xor(s[n][2], m);
            t[3] = __shfl_xor(s[n][3], m);
            s[n] += t;
        }
    }
    // groups 0..3 publish n=g for this wave (groups 4..7 redundant)
    f32x4 sq = (g == 0 || g == 4) ? s[0] : (g == 1 || g == 5) ? s[1]
             : (g == 2 || g == 6) ? s[2] : s[3];
    if (g < 4) swred[g][wv][pq] = sq;
    __syncthreads();

    f32x4 t4[4];
#pragma unroll
    for (int n = 0; n < 4; ++n) {
        f32x4 a = swred[n][0][pq];
#pragma unroll
        for (int w = 1; w < 8; ++w) a += swred[n][w][pq];
        t4[n] = a;
    }
    f32x4 mx;
#pragma unroll
    for (int k = 0; k < 4; ++k)
        mx[k] = fmaxf(fmaxf(t4[0][k], t4[1][k]), fmaxf(t4[2][k], t4[3][k]));
    f32x4 e[4];
#pragma unroll
    for (int n = 0; n < 4; ++n)
#pragma unroll
        for (int k = 0; k < 4; ++k) e[n][k] = __expf(t4[n][k] - mx[k]);
    f32x4 ssum = e[0] + e[1] + e[2] + e[3];
    f32x4 rs;
#pragma unroll
    for (int k = 0; k < 4; ++k) rs[k] = 1.f / ssum[k];
    f32x4 a4[4];
#pragma unroll
    for (int n = 0; n < 4; ++n) a4[n] = e[n] * rs;

    float* outp = out + ((size_t)b * CCh + c0) * PHI + (size_t)hh * WW + wq;
#pragma unroll
    for (int cj = 0; cj < 4; ++cj) {
        f32x2 vv = *(const f32x2*)(vbp + (size_t)cj * PLO);
        f32x4 o = vals[0][cj] * a4[0] + vals[1][cj] * a4[1] +
                  vals[2][cj] * a4[2] + vals[3][cj] * a4[3] +
                  f32x4{vv[0], vv[0], vv[1], vv[1]};
        *(f32x4*)(outp + (size_t)cj * PHI) = o;
    }
}

// ---------------------------------------------------------------------------
extern "C" void kernel_launch(void* const* d_in, const int* in_sizes, int n_in,
                              void* d_out, int out_size, void* d_ws, size_t ws_size,
                              hipStream_t stream) {
    const float* ctx  = (const float*)d_in[0];
    const float* ms   = (const float*)d_in[1];
    const float* Wc_w = (const float*)d_in[2];
    // d_in[3] = Wc_b: constant across n at each pixel -> cancels in softmax.
    const float* Wf_w = (const float*)d_in[4];
    const float* Wf_b = (const float*)d_in[5];
    const float* Wv_w = (const float*)d_in[6];
    const float* Wv_b = (const float*)d_in[7];
    float* out = (float*)d_out;

    char* ws = (char*)d_ws;
    bf16*  ms_t  = (bf16*)ws;                     // 16,777,216 B
    bf16*  Wv_p  = (bf16*)(ws + 16777216);        //  2,359,296 B
    bf16*  M_qk  = (bf16*)(ws + 19136512);        //    262,144 B
    float* d_qk  = (float*)(ws + 19398656);       //      1,024 B
    bf16*  zerob = (bf16*)(ws + 19399680);        //      2,048 B
    bf16*  qk    = (bf16*)(ws + 19401728);        //  8,388,608 B
    float* v     = (float*)(ws + 27790336);       // 16,777,216 B (total ~44.6 MB)

    prep_mqk<<<dim3(2, 256), 256, 0, stream>>>(Wc_w, Wf_w, Wf_b, M_qk, d_qk);
    prep_ms<<<dim3(128, 16, 4), 256, 0, stream>>>(ms, ms_t);
    prep_wv<<<dim3(4608), 256, 0, stream>>>(Wv_w, Wv_p, zerob);
    gemm_kernel<<<dim3(64, 2, 8), 256, 0, stream>>>(Wv_p, M_qk, ms_t, d_qk,
                                                    Wv_b, zerob, v, qk);
    attn_kernel<<<dim3(2048), 512, 0, stream>>>(ctx, qk, v, out);
}

// Round 3
// 503.270 us; speedup vs baseline: 1.0646x; 1.0487x over previous
//
#include <hip/hip_runtime.h>

// Problem constants
#define NB   4      // batch
#define NN   4      // contexts per pixel
#define CCh  256    // Cc
#define CFh  512    // Cf
#define HH   128
#define WW   128
#define PLO  4096   // 64*64 low-res pixels
#define PHI  16384  // 128*128 hi-res pixels

typedef __bf16 bf16;
typedef __bf16 bf16x8 __attribute__((ext_vector_type(8)));
typedef float  f32x4  __attribute__((ext_vector_type(4)));
typedef float  f32x2  __attribute__((ext_vector_type(2)));

__device__ __forceinline__ void gll16(const void* g, void* lds) {
    __builtin_amdgcn_global_load_lds(
        (const __attribute__((address_space(1))) void*)g,
        (__attribute__((address_space(3))) void*)lds, 16, 0, 0);
}

__device__ __forceinline__ unsigned pack2bf(float a, float b) {
    unsigned short ua = __builtin_bit_cast(unsigned short, (bf16)a);
    unsigned short ub = __builtin_bit_cast(unsigned short, (bf16)b);
    return (unsigned)ua | ((unsigned)ub << 16);
}

// ---------------------------------------------------------------------------
// prep 1: M_qk[c][f] = sum_o Wc_w[o][c] * Wf_w[o][f]  (bf16 out)
//         d_qk[c]    = sum_o Wc_w[o][c] * Wf_b[o]     (fp32, parallel reduce)
__global__ void prep_mqk(const float* __restrict__ Wc_w, const float* __restrict__ Wf_w,
                         const float* __restrict__ Wf_b, bf16* __restrict__ M_qk,
                         float* __restrict__ d_qk) {
    __shared__ float red[256];
    int c = blockIdx.y;
    int f = blockIdx.x * 256 + threadIdx.x;
    float s = 0.f;
#pragma unroll 8
    for (int o = 0; o < CCh; ++o)
        s += Wc_w[o * CCh + c] * Wf_w[o * CFh + f];
    M_qk[c * CFh + f] = (bf16)s;
    if (blockIdx.x == 0) {          // block-uniform branch: barriers are safe
        int o = threadIdx.x;
        red[o] = Wc_w[o * CCh + c] * Wf_b[o];
        __syncthreads();
        for (int st = 128; st > 0; st >>= 1) {
            if (threadIdx.x < st) red[threadIdx.x] += red[threadIdx.x + st];
            __syncthreads();
        }
        if (threadIdx.x == 0) d_qk[c] = red[0];
    }
}

// ---------------------------------------------------------------------------
// prep 2: transpose mainstream [B][512][4096] fp32 -> ms_t [B][4096][512] bf16
// Write phase packs 2 bf16 per u32 store (halves store instrs vs scalar bf16).
__global__ void prep_ms(const float* __restrict__ ms, bf16* __restrict__ ms_t) {
    __shared__ float tile[32][33];   // [f_local][p_local]
    int b = blockIdx.z;
    int p0 = blockIdx.x * 32, f0 = blockIdx.y * 32;
    int tx = threadIdx.x;
    int r = tx >> 5, cc = tx & 31;
    const float* src = ms + (size_t)b * CFh * PLO;
#pragma unroll
    for (int q = 0; q < 4; ++q) {
        int fl = q * 8 + r;
        tile[fl][cc] = src[(size_t)(f0 + fl) * PLO + p0 + cc];
    }
    __syncthreads();
    bf16* dst = ms_t + (size_t)b * PLO * CFh;
    int fp = tx & 15;                // f-pair index: f_local = 2*fp, 2*fp+1
    int r2 = tx >> 4;                // 0..15
#pragma unroll
    for (int q = 0; q < 2; ++q) {
        int pl = q * 16 + r2;        // p_local 0..31
        unsigned w = pack2bf(tile[2 * fp][pl], tile[2 * fp + 1][pl]);
        *((unsigned*)(dst + (size_t)(p0 + pl) * CFh + f0) + fp) = w;
    }
}

// ---------------------------------------------------------------------------
// prep 3: pack Wv_w [256][512][3][3] fp32 -> Wv_p [9][256][512] bf16; zero zerobuf
__global__ void prep_wv(const float* __restrict__ Wv_w, bf16* __restrict__ Wv_p,
                        bf16* __restrict__ zerob) {
    int tid = blockIdx.x * 256 + threadIdx.x;   // t-major: (t*256 + c)*512 + f
    int t = tid / (CCh * CFh);
    int rem = tid % (CCh * CFh);
    int c = rem / CFh, f = rem % CFh;
    Wv_p[tid] = (bf16)Wv_w[(size_t)(c * CFh + f) * 9 + t];
    if (tid < 1024) zerob[tid] = (bf16)0.f;
}

// ---------------------------------------------------------------------------
// GEMM: M=channels(128-tile), N=pixels(128-tile), BK=32, 256 thr = 4 waves.
// grid (32, 2, 16): z<12 -> conv tap-group tg=z%3, b=z/3, taps [3tg,3tg+3),
//   writes fp32 partials (no bias) to v3[tg][b][256][4096].
// z>=12 -> qk (1 tap), b=z-12, writes bf16 (+d_qk bias) to qk_out.
// (R0-proven structure: serial stage, compiler-scheduled, 4 blocks/CU.)
__global__ __launch_bounds__(256) void gemm_kernel(
    const bf16* __restrict__ Wv_p,   // [9][256][512]
    const bf16* __restrict__ M_qk,   // [256][512]
    const bf16* __restrict__ ms_t,   // [B][4096][512]
    const float* __restrict__ d_qk,
    const bf16* __restrict__ zerob,
    float* __restrict__ v3, bf16* __restrict__ qk_out) {
    __shared__ __align__(16) bf16 Alds[128 * 32];  // [c][f]
    __shared__ __align__(16) bf16 Blds[128 * 32];  // [p][f]

    const int tx = threadIdx.x;
    const int wave = tx >> 6, lane = tx & 63;
    const int ptile = blockIdx.x, ctile = blockIdx.y;
    const int z = blockIdx.z;
    const int mode = (z >= 12);                 // 0=conv partial, 1=qk
    const int b = mode ? (z - 12) : (z / 3);
    const int tg = mode ? 0 : (z % 3);
    const int t0 = tg * 3;
    const int ntaps = mode ? 1 : 3;

    const bf16* Wbase = mode ? M_qk : (Wv_p + (size_t)t0 * CCh * CFh);
    const bf16* msb = ms_t + (size_t)b * PLO * CFh;

    // staging lane mapping: issue q covers bytes [wave*2048 + q*1024, +1024)
    int idx0 = wave * 2048 + lane * 16;
    int idx1 = idx0 + 1024;
    int rA0 = idx0 >> 6, fq0 = (idx0 >> 4) & 3;   // row 0..127, 16B-chunk 0..3
    int rA1 = idx1 >> 6, fq1 = (idx1 >> 4) & 3;
    const size_t aoff0 = (size_t)(ctile * 128 + rA0) * CFh + fq0 * 8;
    const size_t aoff1 = (size_t)(ctile * 128 + rA1) * CFh + fq1 * 8;
    char* ldsA0 = (char*)Alds + wave * 2048;
    char* ldsA1 = ldsA0 + 1024;
    char* ldsB0 = (char*)Blds + wave * 2048;
    char* ldsB1 = ldsB0 + 1024;

    const int p0 = ptile * 128 + rA0, p1 = ptile * 128 + rA1;
    const int i0 = p0 >> 6, j0 = p0 & 63;
    const int i1 = p1 >> 6, j1 = p1 & 63;

    f32x4 acc[4][4];
#pragma unroll
    for (int mi = 0; mi < 4; ++mi)
#pragma unroll
        for (int ni = 0; ni < 4; ++ni) acc[mi][ni] = f32x4{0.f, 0.f, 0.f, 0.f};

    const int wm = wave >> 1, wn = wave & 1;
    const int quad = lane >> 4, l15 = lane & 15;

    for (int t = 0; t < ntaps; ++t) {
        const int dy = mode ? 0 : ((t0 + t) / 3 - 1);
        const int dx = mode ? 0 : ((t0 + t) % 3 - 1);
        const bf16* Wt = Wbase + (size_t)t * CCh * CFh;
        int si0 = i0 + dy, sj0 = j0 + dx, si1 = i1 + dy, sj1 = j1 + dx;
        bool ok0 = (unsigned)si0 < 64u && (unsigned)sj0 < 64u;
        bool ok1 = (unsigned)si1 < 64u && (unsigned)sj1 < 64u;
        const bf16* bsrc0 = ok0 ? msb + (size_t)(si0 * 64 + sj0) * CFh + fq0 * 8 : zerob;
        const bf16* bsrc1 = ok1 ? msb + (size_t)(si1 * 64 + sj1) * CFh + fq1 * 8 : zerob;

        for (int fc = 0; fc < CFh / 32; ++fc) {
            const int f0 = fc * 32;
            __syncthreads();   // prev compute done before overwriting LDS
            gll16(Wt + aoff0 + f0, ldsA0);
            gll16(Wt + aoff1 + f0, ldsA1);
            gll16(bsrc0 + f0, ldsB0);
            gll16(bsrc1 + f0, ldsB1);
            __syncthreads();

            bf16x8 af[4], bfr[4];
#pragma unroll
            for (int mi = 0; mi < 4; ++mi)
                af[mi] = *(const bf16x8*)&Alds[(wm * 64 + mi * 16 + l15) * 32 + quad * 8];
#pragma unroll
            for (int ni = 0; ni < 4; ++ni)
                bfr[ni] = *(const bf16x8*)&Blds[(wn * 64 + ni * 16 + l15) * 32 + quad * 8];
#pragma unroll
            for (int mi = 0; mi < 4; ++mi)
#pragma unroll
                for (int ni = 0; ni < 4; ++ni)
                    acc[mi][ni] = __builtin_amdgcn_mfma_f32_16x16x32_bf16(
                        af[mi], bfr[ni], acc[mi][ni], 0, 0, 0);
        }
    }

    // C/D layout: col = lane&15 (pixel), row = quad*4 + r (channel)
    if (mode) {
        bf16* obase = qk_out + (size_t)b * CCh * PLO;
#pragma unroll
        for (int mi = 0; mi < 4; ++mi) {
            int cb = ctile * 128 + wm * 64 + mi * 16 + quad * 4;
#pragma unroll
            for (int ni = 0; ni < 4; ++ni) {
                int p = ptile * 128 + wn * 64 + ni * 16 + l15;
                bf16* op = obase + (size_t)cb * PLO + p;
#pragma unroll
                for (int r = 0; r < 4; ++r)
                    op[(size_t)r * PLO] = (bf16)(acc[mi][ni][r] + d_qk[cb + r]);
            }
        }
    } else {
        float* obase = v3 + (size_t)(tg * NB + b) * CCh * PLO;
#pragma unroll
        for (int mi = 0; mi < 4; ++mi) {
            int cb = ctile * 128 + wm * 64 + mi * 16 + quad * 4;
#pragma unroll
            for (int ni = 0; ni < 4; ++ni) {
                int p = ptile * 128 + wn * 64 + ni * 16 + l15;
                float* op = obase + (size_t)cb * PLO + p;
#pragma unroll
                for (int r = 0; r < 4; ++r)
                    op[(size_t)r * PLO] = acc[mi][ni][r];
            }
        }
    }
}

// ---------------------------------------------------------------------------
// attention, single ctx pass: block = 512 thr, 64 pixels (one 64-wide w strip).
// Thread: 4 consecutive w-pixels (f32x4 lanes) x 8 channels x 4 n held in VGPRs.
// Phase 1: load ctx (dwordx4) + dot with qk. Phase 2: shfl+LDS reduce, softmax.
// Phase 3: weighted sum from VGPRs + conv partials + bias -> out.
// (R0-proven structure.)
__global__ __launch_bounds__(512) void attn_kernel(
    const float* __restrict__ ctx,   // [4][4][256][128][128]
    const bf16* __restrict__ qk,     // [4][256][4096]
    const float* __restrict__ v3,    // [3][4][256][4096] conv partials
    const float* __restrict__ Wv_b,  // [256]
    float* __restrict__ out) {       // [4][256][128][128]
    __shared__ f32x4 swred[4][8][16];  // [n][wave][pq]
    const int tx = threadIdx.x;
    const int pq = tx & 15;            // which 4-pixel group
    const int cc = tx >> 4;            // channel chunk 0..31
    const int lane = tx & 63;
    const int wv = tx >> 6;
    const int quad = lane >> 4;

    const int pbase = blockIdx.x << 6;
    const int b = pbase >> 14;
    const int rem = pbase & 16383;
    const int hh = rem >> 7;
    const int w0 = rem & 127;          // 0 or 64
    const int wq = w0 + pq * 4;
    const int i = hh >> 1, j0 = wq >> 1;   // j0 even

    const int c0 = cc * 8;
    const size_t NSTR = (size_t)CCh * PHI;
    const float* cbase = ctx + (size_t)b * NN * NSTR + (size_t)c0 * PHI
                             + (size_t)hh * WW + wq;
    const bf16* qkb = qk + ((size_t)b * CCh + c0) * PLO + i * 64 + j0;
    const float* vbp = v3 + ((size_t)b * CCh + c0) * PLO + i * 64 + j0;

    f32x4 vals[4][8];
    f32x4 s[4];
#pragma unroll
    for (int n = 0; n < 4; ++n) s[n] = f32x4{0.f, 0.f, 0.f, 0.f};

#pragma unroll
    for (int cj = 0; cj < 8; ++cj) {
        unsigned qw = *(const unsigned*)(qkb + (size_t)cj * PLO);
        float qa = __uint_as_float(qw << 16);
        float qb = __uint_as_float(qw & 0xffff0000u);
        f32x4 qv = {qa, qa, qb, qb};
#pragma unroll
        for (int n = 0; n < 4; ++n) {
            vals[n][cj] = *(const f32x4*)(cbase + n * NSTR + (size_t)cj * PHI);
            s[n] += vals[n][cj] * qv;
        }
    }
    // reduce over the 4 quads within each wave (cc bits 0..1 live in lane bits 4..5)
#pragma unroll
    for (int n = 0; n < 4; ++n) {
#pragma unroll
        for (int m = 16; m <= 32; m <<= 1) {
            f32x4 t;
            t[0] = __shfl_xor(s[n][0], m);
            t[1] = __shfl_xor(s[n][1], m);
            t[2] = __shfl_xor(s[n][2], m);
            t[3] = __shfl_xor(s[n][3], m);
            s[n] += t;
        }
    }
    // lane with quad q publishes n=q for its wave
    f32x4 sq = (quad == 0) ? s[0] : (quad == 1) ? s[1] : (quad == 2) ? s[2] : s[3];
    swred[quad][wv][pq] = sq;
    __syncthreads();

    f32x4 t4[4];
#pragma unroll
    for (int n = 0; n < 4; ++n) {
        f32x4 a = swred[n][0][pq];
#pragma unroll
        for (int w = 1; w < 8; ++w) a += swred[n][w][pq];
        t4[n] = a;
    }
    f32x4 mx;
#pragma unroll
    for (int k = 0; k < 4; ++k)
        mx[k] = fmaxf(fmaxf(t4[0][k], t4[1][k]), fmaxf(t4[2][k], t4[3][k]));
    f32x4 e[4];
#pragma unroll
    for (int n = 0; n < 4; ++n)
#pragma unroll
        for (int k = 0; k < 4; ++k) e[n][k] = __expf(t4[n][k] - mx[k]);
    f32x4 ssum = e[0] + e[1] + e[2] + e[3];
    f32x4 a4[4];
#pragma unroll
    for (int n = 0; n < 4; ++n)
#pragma unroll
        for (int k = 0; k < 4; ++k) a4[n][k] = e[n][k] / ssum[k];

    float* outp = out + ((size_t)b * CCh + c0) * PHI + (size_t)hh * WW + wq;
#pragma unroll
    for (int cj = 0; cj < 8; ++cj) {
        f32x2 vv = *(const f32x2*)(vbp + (size_t)cj * PLO);
        vv += *(const f32x2*)(vbp + 4194304 + (size_t)cj * PLO);
        vv += *(const f32x2*)(vbp + 8388608 + (size_t)cj * PLO);
        float bc = Wv_b[c0 + cj];
        float va = vv[0] + bc, vb2 = vv[1] + bc;
        f32x4 o = vals[0][cj] * a4[0] + vals[1][cj] * a4[1] +
                  vals[2][cj] * a4[2] + vals[3][cj] * a4[3] +
                  f32x4{va, va, vb2, vb2};
        *(f32x4*)(outp + (size_t)cj * PHI) = o;
    }
}

// ---------------------------------------------------------------------------
extern "C" void kernel_launch(void* const* d_in, const int* in_sizes, int n_in,
                              void* d_out, int out_size, void* d_ws, size_t ws_size,
                              hipStream_t stream) {
    const float* ctx  = (const float*)d_in[0];
    const float* ms   = (const float*)d_in[1];
    const float* Wc_w = (const float*)d_in[2];
    // d_in[3] = Wc_b: constant across n at each pixel -> cancels in softmax.
    const float* Wf_w = (const float*)d_in[4];
    const float* Wf_b = (const float*)d_in[5];
    const float* Wv_w = (const float*)d_in[6];
    const float* Wv_b = (const float*)d_in[7];
    float* out = (float*)d_out;

    char* ws = (char*)d_ws;
    bf16*  ms_t  = (bf16*)ws;                     // 16,777,216 B
    bf16*  Wv_p  = (bf16*)(ws + 16777216);        //  2,359,296 B
    bf16*  M_qk  = (bf16*)(ws + 19136512);        //    262,144 B
    float* d_qk  = (float*)(ws + 19398656);       //      1,024 B
    bf16*  zerob = (bf16*)(ws + 19399680);        //      2,048 B
    bf16*  qk    = (bf16*)(ws + 19401728);        //  8,388,608 B
    float* v3    = (float*)(ws + 27790336);       // 50,331,648 B (total ~78.1 MB)

    prep_mqk<<<dim3(2, 256), 256, 0, stream>>>(Wc_w, Wf_w, Wf_b, M_qk, d_qk);
    prep_ms<<<dim3(128, 16, 4), 256, 0, stream>>>(ms, ms_t);
    prep_wv<<<dim3(4608), 256, 0, stream>>>(Wv_w, Wv_p, zerob);
    gemm_kernel<<<dim3(32, 2, 16), 256, 0, stream>>>(Wv_p, M_qk, ms_t, d_qk,
                                                     zerob, v3, qk);
    attn_kernel<<<dim3(1024), 512, 0, stream>>>(ctx, qk, v3, Wv_b, out);
}